// Round 1
// baseline (797.448 us; speedup 1.0000x reference)
//
#include <hip/hip_runtime.h>
#include <stdint.h>
#include <stddef.h>

// ---------------------------------------------------------------------------
// InverseImportanceLinear: out = x @ W_deq^T + bias
//   W_deq[k,n] = (Q[k,n] - zeros[k,n/64]) * scales[k,n/64] * mu2[k] * mu1[n]
// Strategy: dequant W -> bf16 (workspace), convert x -> bf16 (workspace),
// then m97-style bf16 MFMA GEMM (C = A @ B^T layout, both row-major over
// the contraction dim), bias fused in epilogue. fp32 output.
// ---------------------------------------------------------------------------

typedef __attribute__((ext_vector_type(8))) short bfrag;   // 8 bf16 = 4 VGPRs
typedef __attribute__((ext_vector_type(4))) float f32x4;
typedef __attribute__((ext_vector_type(4))) int   i32x4;

__device__ __forceinline__ short f2bf(float f) {
    uint32_t u = __float_as_uint(f);
    u += 0x7fffu + ((u >> 16) & 1u);        // round-to-nearest-even
    return (short)(u >> 16);
}

__device__ __forceinline__ void gload_lds16(const void* g, void* l) {
    __builtin_amdgcn_global_load_lds(
        (const __attribute__((address_space(1))) void*)g,
        (__attribute__((address_space(3))) void*)l,
        16, 0, 0);
}

// ---- phase 1a: x fp32 -> bf16 -------------------------------------------
__global__ void cvt_x_kernel(const float* __restrict__ x, short* __restrict__ xb) {
    int i = blockIdx.x * 256 + threadIdx.x;          // 8-element chunk index
    const f32x4* xv = (const f32x4*)x;
    f32x4 a = xv[2 * i];
    f32x4 b = xv[2 * i + 1];
    bfrag o;
    o[0] = f2bf(a[0]); o[1] = f2bf(a[1]); o[2] = f2bf(a[2]); o[3] = f2bf(a[3]);
    o[4] = f2bf(b[0]); o[5] = f2bf(b[1]); o[6] = f2bf(b[2]); o[7] = f2bf(b[3]);
    ((bfrag*)xb)[i] = o;
}

// ---- phase 1b: dequant W rows [k0, k0+rows) -> bf16 ---------------------
// GROUP_SIZE = 64; each thread handles 8 contiguous n (same group).
__global__ void deq_w_kernel(const int* __restrict__ Q,
                             const float* __restrict__ scales,
                             const float* __restrict__ zeros,
                             const float* __restrict__ mu1,
                             const float* __restrict__ mu2,
                             short* __restrict__ wb,
                             int k0, int N, int NG) {
    int kl = blockIdx.y;
    int kg = k0 + kl;
    int c  = blockIdx.x * 256 + threadIdx.x;         // 8-elem chunk within row
    int n0 = c << 3;
    int g  = n0 >> 6;
    float s = scales[(size_t)kg * NG + g] * mu2[kg];
    float z = zeros[(size_t)kg * NG + g];
    const i32x4* qv = (const i32x4*)(Q + (size_t)kg * N + n0);
    i32x4 q0 = qv[0];
    i32x4 q1 = qv[1];
    const f32x4* uv = (const f32x4*)(mu1 + n0);
    f32x4 u0 = uv[0];
    f32x4 u1 = uv[1];
    bfrag o;
    o[0] = f2bf(((float)q0[0] - z) * s * u0[0]);
    o[1] = f2bf(((float)q0[1] - z) * s * u0[1]);
    o[2] = f2bf(((float)q0[2] - z) * s * u0[2]);
    o[3] = f2bf(((float)q0[3] - z) * s * u0[3]);
    o[4] = f2bf(((float)q1[0] - z) * s * u1[0]);
    o[5] = f2bf(((float)q1[1] - z) * s * u1[1]);
    o[6] = f2bf(((float)q1[2] - z) * s * u1[2]);
    o[7] = f2bf(((float)q1[3] - z) * s * u1[3]);
    ((bfrag*)wb)[(size_t)kl * (N >> 3) + c] = o;
}

// ---- phase 2: bf16 GEMM, C = A @ B^T + bias -----------------------------
// A: M x Kc bf16 row-major (x). B: rows x Kc bf16 row-major (W chunk).
// C: M x Nout fp32, this launch fills columns [col0, col0 + rows).
#define BM 128
#define BN 128
#define BK 32

__global__ void gemm_bt_kernel(const short* __restrict__ A,
                               const short* __restrict__ B,
                               const float* __restrict__ bias,
                               float* __restrict__ C,
                               int Kc, int Nout, int col0) {
    __shared__ __attribute__((aligned(16))) short As[BM * BK];
    __shared__ __attribute__((aligned(16))) short Bs[BN * BK];

    const int tid  = threadIdx.x;
    const int lane = tid & 63;
    const int wave = tid >> 6;
    const int wm   = (wave >> 1) * 64;     // wave's 64-row quadrant
    const int wn   = (wave & 1) * 64;      // wave's 64-col quadrant
    const int bm   = blockIdx.y * BM;      // global row base
    const int bnl  = blockIdx.x * BN;      // local col base (within chunk)

    f32x4 acc[4][4];
#pragma unroll
    for (int i = 0; i < 4; i++)
#pragma unroll
        for (int j = 0; j < 4; j++)
            acc[i][j] = (f32x4){0.f, 0.f, 0.f, 0.f};

    // staging: chunk c (16B) -> LDS [m = c>>2][k = (c&3)*8]; two calls cover
    // 128 rows x 32 cols. Per-lane LDS ptr order matches global_load_lds's
    // wave-uniform-base + lane*16 rule.
    const short* gA  = A + (size_t)(bm + (tid >> 2)) * Kc + (tid & 3) * 8;
    const short* gA2 = gA + (size_t)64 * Kc;
    const short* gB  = B + (size_t)(bnl + (tid >> 2)) * Kc + (tid & 3) * 8;
    const short* gB2 = gB + (size_t)64 * Kc;
    short* lA  = As + tid * 8;
    short* lA2 = As + 2048 + tid * 8;
    short* lB  = Bs + tid * 8;
    short* lB2 = Bs + 2048 + tid * 8;

    const int r  = lane & 15;              // row within 16x16 tile
    const int ko = (lane >> 4) * 8;        // k offset of this lane's fragment
    const short* pa = As + (wm + r) * BK + ko;
    const short* pb = Bs + (wn + r) * BK + ko;

    for (int k0 = 0; k0 < Kc; k0 += BK) {
        gload_lds16(gA + k0, lA);
        gload_lds16(gA2 + k0, lA2);
        gload_lds16(gB + k0, lB);
        gload_lds16(gB2 + k0, lB2);
        __syncthreads();                   // drains vmcnt, tiles visible

        bfrag af[4], bfv[4];
#pragma unroll
        for (int i = 0; i < 4; i++) af[i]  = *(const bfrag*)(pa + i * 16 * BK);
#pragma unroll
        for (int j = 0; j < 4; j++) bfv[j] = *(const bfrag*)(pb + j * 16 * BK);

#pragma unroll
        for (int i = 0; i < 4; i++)
#pragma unroll
            for (int j = 0; j < 4; j++)
                acc[i][j] = __builtin_amdgcn_mfma_f32_16x16x32_bf16(
                    af[i], bfv[j], acc[i][j], 0, 0, 0);

        __syncthreads();                   // reads done before next overwrite
    }

    // epilogue: C/D layout col = lane&15, row = (lane>>4)*4 + reg
    const int row0  = bm + wm + (lane >> 4) * 4;
    const int colg0 = col0 + bnl + wn;
#pragma unroll
    for (int j = 0; j < 4; j++) {
        int col  = colg0 + j * 16 + r;
        float bv = bias[col];
#pragma unroll
        for (int i = 0; i < 4; i++) {
            int row = row0 + i * 16;
#pragma unroll
            for (int q = 0; q < 4; q++)
                C[(size_t)(row + q) * Nout + col] = acc[i][j][q] + bv;
        }
    }
}

// ---- emergency fallback (workspace too small) ---------------------------
__global__ void naive_kernel(const float* __restrict__ x, const int* __restrict__ Q,
                             const float* __restrict__ scales, const float* __restrict__ zeros,
                             const float* __restrict__ mu1, const float* __restrict__ mu2,
                             const float* __restrict__ bias, float* __restrict__ out,
                             int T, int N, int K, int NG) {
    long long total = (long long)T * K;
    for (long long idx = blockIdx.x * 256ll + threadIdx.x; idx < total;
         idx += (long long)gridDim.x * 256ll) {
        int t = (int)(idx / K);
        int k = (int)(idx - (long long)t * K);
        float s = 0.f;
        for (int n = 0; n < N; n++) {
            int g = n >> 6;
            float w = ((float)Q[(size_t)k * N + n] - zeros[(size_t)k * NG + g]) *
                      scales[(size_t)k * NG + g];
            s += x[(size_t)t * N + n] * w * mu1[n];
        }
        out[idx] = s * mu2[k] + bias[k];
    }
}

extern "C" void kernel_launch(void* const* d_in, const int* in_sizes, int n_in,
                              void* d_out, int out_size, void* d_ws, size_t ws_size,
                              hipStream_t stream) {
    const float* x      = (const float*)d_in[0];
    const int*   Q      = (const int*)d_in[1];
    const float* scales = (const float*)d_in[2];
    const float* zeros  = (const float*)d_in[3];
    const float* mu1    = (const float*)d_in[4];
    const float* mu2    = (const float*)d_in[5];
    const float* bias   = (const float*)d_in[6];
    float* out = (float*)d_out;

    const int N  = in_sizes[4];            // 4096 (contraction)
    const int K  = in_sizes[5];            // 11264 (output cols)
    const int T  = in_sizes[0] / N;        // 4096 (output rows)
    const int NG = in_sizes[2] / K;        // 64 groups

    const size_t xb_bytes  = (size_t)T * N * 2;      // x in bf16
    const size_t row_bytes = (size_t)N * 2;          // one W row in bf16

    if (ws_size < xb_bytes + 128 * row_bytes) {
        naive_kernel<<<4096, 256, 0, stream>>>(x, Q, scales, zeros, mu1, mu2,
                                               bias, out, T, N, K, NG);
        return;
    }

    short* xb = (short*)d_ws;
    short* wb = (short*)((char*)d_ws + xb_bytes);
    size_t max_rows = (ws_size - xb_bytes) / row_bytes;
    int CH = (int)((max_rows / 128) * 128);
    if (CH > K) CH = K;

    cvt_x_kernel<<<(T * N / 8) / 256, 256, 0, stream>>>(x, xb);

    for (int c0 = 0; c0 < K; c0 += CH) {
        int rows = (K - c0 < CH) ? (K - c0) : CH;
        dim3 dgrid(N / (8 * 256), rows);
        deq_w_kernel<<<dgrid, 256, 0, stream>>>(Q, scales, zeros, mu1, mu2, wb,
                                                c0, N, NG);
        dim3 ggrid(rows / BN, T / BM);
        gemm_bt_kernel<<<ggrid, 256, 0, stream>>>(xb, wb, bias, out, N, K, c0);
    }
}